// Round 5
// baseline (9237.772 us; speedup 1.0000x reference)
//
#include <hip/hip_runtime.h>

#define N_NODES 50000
#define L_SCALES 4
#define E_NNZ 1600000
#define C 128
#define NL (N_NODES * L_SCALES)

#define OVF_CAP 8192

#define RPB 16                    // rows per bucket
#define NB (N_NODES / RPB)        // 3125 buckets (exact: 3125*16 = 50000)
#define NSUB 8                    // per-XCD sub-regions for partition writes
#define SCAP 112                  // capacity per (sub, bucket); mean 64, sigma 8
#define BT_STRIDE 16              // pad tail counters to one per 64B line

#define NCS 8                     // channel slices (one per XCD, heuristic blockIdx%8)
#define CS 16                     // channels per slice; X slice = N*64B = 3.2 MB < 4 MB L2

// ---------------- Fused GEMM over all scales: Y[r,c] = sum_k feat[r,k]*W[k,c], r in [0, N*L) ----------------
// 8x8 register micro-tile per thread; A staged transposed (pad 132) + W staged, both in LDS.
__global__ __launch_bounds__(256) void gemm_all(
    const float* __restrict__ feat,   // [NL, C]
    const float* __restrict__ W,      // [C, C]
    float* __restrict__ Y)            // [NL, C]  (aliases d_out)
{
    __shared__ float As[16][132];     // As[kk][row], padded: 8.4 KB
    __shared__ float Ws[16][128];     // Ws[kk][col]: 8 KB

    int t  = threadIdx.x;
    int ty = t >> 4;                  // 0..15 -> rows ty*8..+7
    int tx = t & 15;                  // 0..15 -> cols tx*4..+3 and 64+tx*4..+3
    size_t r0 = (size_t)blockIdx.x * 128;

    float acc[8][8];
    #pragma unroll
    for (int i = 0; i < 8; ++i)
        #pragma unroll
        for (int j = 0; j < 8; ++j) acc[i][j] = 0.f;

    for (int kt = 0; kt < C; kt += 16) {
        __syncthreads();
        #pragma unroll
        for (int jj = 0; jj < 2; ++jj) {
            int q = t + 256 * jj;
            // A tile: 128 rows x 16 k, transposed into As[kk][row]
            int row = q >> 2, pc = q & 3;
            size_t r = r0 + row;
            float4 f = (r < (size_t)NL) ? ((const float4*)(feat + r * C + kt))[pc]
                                        : make_float4(0.f, 0.f, 0.f, 0.f);
            As[pc * 4 + 0][row] = f.x;
            As[pc * 4 + 1][row] = f.y;
            As[pc * 4 + 2][row] = f.z;
            As[pc * 4 + 3][row] = f.w;
            // W tile: 16 k-rows x 128 cols, natural layout
            int kr = q >> 5, wpc = q & 31;
            ((float4*)&Ws[kr][0])[wpc] = ((const float4*)(W + (size_t)(kt + kr) * C))[wpc];
        }
        __syncthreads();

        #pragma unroll
        for (int kk = 0; kk < 16; ++kk) {
            float4 a0 = *(const float4*)&As[kk][ty * 8];
            float4 a1 = *(const float4*)&As[kk][ty * 8 + 4];
            float4 w0 = *(const float4*)&Ws[kk][tx * 4];
            float4 w1 = *(const float4*)&Ws[kk][64 + tx * 4];
            float a[8] = {a0.x, a0.y, a0.z, a0.w, a1.x, a1.y, a1.z, a1.w};
            float w[8] = {w0.x, w0.y, w0.z, w0.w, w1.x, w1.y, w1.z, w1.w};
            #pragma unroll
            for (int i = 0; i < 8; ++i)
                #pragma unroll
                for (int j = 0; j < 8; ++j)
                    acc[i][j] = fmaf(a[i], w[j], acc[i][j]);
        }
    }

    #pragma unroll
    for (int i = 0; i < 8; ++i) {
        size_t r = r0 + ty * 8 + i;
        if (r < (size_t)NL) {
            float* orow = Y + r * C;
            *(float4*)(orow + tx * 4)      = make_float4(acc[i][0], acc[i][1], acc[i][2], acc[i][3]);
            *(float4*)(orow + 64 + tx * 4) = make_float4(acc[i][4], acc[i][5], acc[i][6], acc[i][7]);
        }
    }
}

// ---------------- Pass 1: partition edges into 16-row buckets, packed 8B records ----------------
__global__ __launch_bounds__(256) void partition_edges(
    const int*   __restrict__ rows,
    const int*   __restrict__ cols,
    const float* __restrict__ vals,
    uint2* __restrict__ bkt,          // [NSUB][NB][SCAP]
    int*   __restrict__ btail,        // [NSUB][NB] stride BT_STRIDE
    int* __restrict__ ovf_n, int* __restrict__ ovf_row,
    int* __restrict__ ovf_col, float* __restrict__ ovf_val)
{
    int e = blockIdx.x * 256 + threadIdx.x;
    if (e >= E_NNZ) return;
    int s = blockIdx.x & (NSUB - 1);  // heuristic XCD id: same-s blocks share an XCD L2
    int r = rows[e];
    int c = cols[e];
    float v = vals[e];
    int b = r >> 4;                   // RPB = 16
    int pos = atomicAdd(&btail[(s * NB + b) * BT_STRIDE], 1);
    if (pos < SCAP) {
        // col fits in 16 bits (N=50000 < 65536); rowlo in bits 16..19
        bkt[((size_t)s * NB + b) * SCAP + pos] =
            make_uint2((unsigned)c | ((unsigned)(r & (RPB - 1)) << 16), __float_as_uint(v));
    } else {                          // statistically never (z ~ 6 sigma); correctness fallback
        int k = atomicAdd(ovf_n, 1);
        if (k < OVF_CAP) { ovf_row[k] = r; ovf_col[k] = c; ovf_val[k] = v; }
    }
}

// ---------------- SpMM directly from buckets, channel-sliced across XCDs ----------------
// Block = (bucket of 16 rows) x (16-ch slice). slice = blockIdx&7 -> round-robin XCD mapping
// pins each slice's X footprint (N x 64B lines = 3.2 MB) into ONE XCD's 4 MB L2.
// Edges staged to LDS once per block; 16x16 fp32 tile accumulated via ds_add_f32; no ELL array.
__global__ __launch_bounds__(256) void spmm_bucket(
    const uint2* __restrict__ bkt,
    const int*   __restrict__ btail,
    const int*   __restrict__ ovf_n,
    const int*   __restrict__ ovf_row,
    const int*   __restrict__ ovf_col,
    const float* __restrict__ ovf_val,
    const float* __restrict__ X,          // row stride x_stride (floats)
    const float* __restrict__ row_scale,  // nullptr or theta[N]
    float*       __restrict__ out,        // row stride out_stride (floats)
    int x_stride, int out_stride)
{
    __shared__ uint2 eb[NSUB * SCAP];     // up to 896 edges, 7 KB
    __shared__ float acc[RPB][CS];        // 1 KB

    int t   = threadIdx.x;
    int cs  = blockIdx.x & (NCS - 1);     // channel slice -> XCD (heuristic)
    int b   = blockIdx.x >> 3;            // bucket id 0..NB-1
    int chb = cs * CS;

    ((float*)acc)[t] = 0.f;

    // Sub-bucket counts -> prefix offsets (uniform per block; scalar loads, no sync needed)
    int ofs[NSUB + 1];
    ofs[0] = 0;
    #pragma unroll
    for (int s = 0; s < NSUB; ++s) {
        int n = btail[(s * NB + b) * BT_STRIDE];
        ofs[s + 1] = ofs[s] + (n < SCAP ? n : SCAP);
    }
    // Stage all sub-buckets contiguously into LDS (coalesced)
    #pragma unroll
    for (int s = 0; s < NSUB; ++s) {
        int base = ofs[s], n = ofs[s + 1] - base;
        for (int i = t; i < n; i += 256)
            eb[base + i] = bkt[((size_t)s * NB + b) * SCAP + i];
    }
    int total = ofs[NSUB];
    __syncthreads();

    // Per block-iteration: 16 edges x 16 ch. Within a wave: 4 edges x 16 ch ->
    // each edge's gather is exactly one 64B line (L2-resident slice).
    int es = t >> 4;                      // edge sub-slot 0..15
    int ch = t & 15;
    for (int e0 = 0; e0 < total; e0 += 16) {
        int e = e0 + es;
        if (e < total) {
            uint2 rec = eb[e];            // 8B broadcast to 16 lanes, conflict-free
            int   col = (int)(rec.x & 0xFFFFu);
            int   rl  = (int)(rec.x >> 16);
            float v   = __uint_as_float(rec.y);
            float x   = X[(size_t)col * x_stride + chb + ch];
            atomicAdd(&acc[rl][ch], v * x);   // ds_add_f32
        }
    }

    // Overflow fallback (expected never)
    int m = *ovf_n;
    if (m > 0) {
        if (m > OVF_CAP) m = OVF_CAP;
        if (t < CS) {
            for (int k = 0; k < m; ++k) {
                int r = ovf_row[k];
                if ((r >> 4) == b) {
                    float x = X[(size_t)ovf_col[k] * x_stride + chb + t];
                    atomicAdd(&acc[r & (RPB - 1)][t], ovf_val[k] * x);
                }
            }
        }
    }
    __syncthreads();

    int row = b * RPB + (t >> 4);         // always < N_NODES (NB*RPB == N)
    float r = acc[t >> 4][t & 15];
    if (row_scale) r *= row_scale[row];
    out[(size_t)row * out_stride + chb + (t & 15)] = r;
}

extern "C" void kernel_launch(void* const* d_in, const int* in_sizes, int n_in,
                              void* d_out, int out_size, void* d_ws, size_t ws_size,
                              hipStream_t stream) {
    const int*   phi_idx  = (const int*)  d_in[0];   // [L, 2, E]
    const float* phi_val  = (const float*)d_in[1];   // [L, E]
    const int*   pinv_idx = (const int*)  d_in[2];   // [L, 2, E]
    const float* pinv_val = (const float*)d_in[3];   // [L, E]
    const float* feat     = (const float*)d_in[4];   // [N, L, C] == [NL, C]
    const float* W        = (const float*)d_in[5];   // [C, C]
    const float* theta    = (const float*)d_in[6];   // [N]
    float* out = (float*)d_out;

    // Workspace layout (~49.7 MB; ELL array eliminated)
    float* Z       = (float*)d_ws;                               // N*C f32          25.6 MB
    uint2* bkt     = (uint2*)(Z + (size_t)N_NODES * C);          // NSUB*NB*SCAP     22.4 MB
    int*   btail   = (int*)(bkt + (size_t)NSUB * NB * SCAP);     // NSUB*NB*16        1.6 MB
    int*   ovf_n   = btail + NSUB * NB * BT_STRIDE;              // 1 (adjacent for single memset)
    int*   ovf_row = ovf_n + 1;
    int*   ovf_col = ovf_row + OVF_CAP;
    float* ovf_val = (float*)(ovf_col + OVF_CAP);

    dim3 blk(256);
    int gemmGrid = (NL + 127) / 128;          // 1563
    int partGrid = (E_NNZ + 255) / 256;       // 6250
    int spmmGrid = NB * NCS;                  // 25000: (bucket, ch-slice)

    // All four scales' feat @ W in one shot, written into out (scratch; each slice
    // out[:,l,:] is consumed by scale-l spmm-1 strictly before spmm-2 overwrites it).
    gemm_all<<<gemmGrid, blk, 0, stream>>>(feat, W, out);

    for (int l = 0; l < L_SCALES; ++l) {
        // ---- Z = theta (.) (phi_inv_l @ out[:,l,:]) ----
        hipMemsetAsync(btail, 0, (NSUB * NB * BT_STRIDE + 1) * sizeof(int), stream);
        partition_edges<<<partGrid, blk, 0, stream>>>(
            pinv_idx + (size_t)l * 2 * E_NNZ,
            pinv_idx + (size_t)l * 2 * E_NNZ + E_NNZ,
            pinv_val + (size_t)l * E_NNZ,
            bkt, btail, ovf_n, ovf_row, ovf_col, ovf_val);
        spmm_bucket<<<spmmGrid, blk, 0, stream>>>(
            bkt, btail, ovf_n, ovf_row, ovf_col, ovf_val,
            out + (size_t)l * C, theta, Z, L_SCALES * C, C);

        // ---- out[:,l,:] = phi_l @ Z ----
        hipMemsetAsync(btail, 0, (NSUB * NB * BT_STRIDE + 1) * sizeof(int), stream);
        partition_edges<<<partGrid, blk, 0, stream>>>(
            phi_idx + (size_t)l * 2 * E_NNZ,
            phi_idx + (size_t)l * 2 * E_NNZ + E_NNZ,
            phi_val + (size_t)l * E_NNZ,
            bkt, btail, ovf_n, ovf_row, ovf_col, ovf_val);
        spmm_bucket<<<spmmGrid, blk, 0, stream>>>(
            bkt, btail, ovf_n, ovf_row, ovf_col, ovf_val,
            Z, nullptr, out + (size_t)l * C, C, L_SCALES * C);
    }
}

// Round 6
// 1702.375 us; speedup vs baseline: 5.4264x; 5.4264x over previous
//
#include <hip/hip_runtime.h>

#define N_NODES 50000
#define L_SCALES 4
#define E_NNZ 1600000
#define C 128
#define NL (N_NODES * L_SCALES)

#define ELL_W 64
#define OVF_CAP 8192

#define RPB 16                    // rows per bucket
#define NB (N_NODES / RPB)        // 3125 buckets (exact: 3125*16 = 50000)
#define NSUB 8                    // per-XCD sub-regions for partition writes
#define SCAP 112                  // capacity per (sub, bucket); mean 64, sigma 8
#define BT_STRIDE 16              // pad tail counters to one per 64B line

// ---------------- Fused GEMM over all scales: Y[r,c] = sum_k feat[r,k]*W[k,c], r in [0, N*L) ----------------
// 8x8 register micro-tile per thread; A staged transposed (pad 132) + W staged, both in LDS.
__global__ __launch_bounds__(256) void gemm_all(
    const float* __restrict__ feat,   // [NL, C]
    const float* __restrict__ W,      // [C, C]
    float* __restrict__ Y)            // [NL, C]  (aliases d_out)
{
    __shared__ float As[16][132];     // As[kk][row], padded: 8.4 KB
    __shared__ float Ws[16][128];     // Ws[kk][col]: 8 KB

    int t  = threadIdx.x;
    int ty = t >> 4;                  // 0..15 -> rows ty*8..+7
    int tx = t & 15;                  // 0..15 -> cols tx*4..+3 and 64+tx*4..+3
    size_t r0 = (size_t)blockIdx.x * 128;

    float acc[8][8];
    #pragma unroll
    for (int i = 0; i < 8; ++i)
        #pragma unroll
        for (int j = 0; j < 8; ++j) acc[i][j] = 0.f;

    for (int kt = 0; kt < C; kt += 16) {
        __syncthreads();
        #pragma unroll
        for (int jj = 0; jj < 2; ++jj) {
            int q = t + 256 * jj;
            // A tile: 128 rows x 16 k, transposed into As[kk][row]
            int row = q >> 2, pc = q & 3;
            size_t r = r0 + row;
            float4 f = (r < (size_t)NL) ? ((const float4*)(feat + r * C + kt))[pc]
                                        : make_float4(0.f, 0.f, 0.f, 0.f);
            As[pc * 4 + 0][row] = f.x;
            As[pc * 4 + 1][row] = f.y;
            As[pc * 4 + 2][row] = f.z;
            As[pc * 4 + 3][row] = f.w;
            // W tile: 16 k-rows x 128 cols, natural layout
            int kr = q >> 5, wpc = q & 31;
            ((float4*)&Ws[kr][0])[wpc] = ((const float4*)(W + (size_t)(kt + kr) * C))[wpc];
        }
        __syncthreads();

        #pragma unroll
        for (int kk = 0; kk < 16; ++kk) {
            float4 a0 = *(const float4*)&As[kk][ty * 8];
            float4 a1 = *(const float4*)&As[kk][ty * 8 + 4];
            float4 w0 = *(const float4*)&Ws[kk][tx * 4];
            float4 w1 = *(const float4*)&Ws[kk][64 + tx * 4];
            float a[8] = {a0.x, a0.y, a0.z, a0.w, a1.x, a1.y, a1.z, a1.w};
            float w[8] = {w0.x, w0.y, w0.z, w0.w, w1.x, w1.y, w1.z, w1.w};
            #pragma unroll
            for (int i = 0; i < 8; ++i)
                #pragma unroll
                for (int j = 0; j < 8; ++j)
                    acc[i][j] = fmaf(a[i], w[j], acc[i][j]);
        }
    }

    #pragma unroll
    for (int i = 0; i < 8; ++i) {
        size_t r = r0 + ty * 8 + i;
        if (r < (size_t)NL) {
            float* orow = Y + r * C;
            *(float4*)(orow + tx * 4)      = make_float4(acc[i][0], acc[i][1], acc[i][2], acc[i][3]);
            *(float4*)(orow + 64 + tx * 4) = make_float4(acc[i][4], acc[i][5], acc[i][6], acc[i][7]);
        }
    }
}

// ---------------- Pass 1: partition edges into 16-row buckets, packed 8B records ----------------
__global__ __launch_bounds__(256) void partition_edges(
    const int*   __restrict__ rows,
    const int*   __restrict__ cols,
    const float* __restrict__ vals,
    uint2* __restrict__ bkt,          // [NSUB][NB][SCAP]
    int*   __restrict__ btail,        // [NSUB][NB] stride BT_STRIDE
    int* __restrict__ ovf_n, int* __restrict__ ovf_row,
    int* __restrict__ ovf_col, float* __restrict__ ovf_val)
{
    int e = blockIdx.x * 256 + threadIdx.x;
    if (e >= E_NNZ) return;
    int s = blockIdx.x & (NSUB - 1);  // heuristic XCD id: same-s blocks share an XCD L2
    int r = rows[e];
    int c = cols[e];
    float v = vals[e];
    int b = r >> 4;                   // RPB = 16
    int pos = atomicAdd(&btail[(s * NB + b) * BT_STRIDE], 1);
    if (pos < SCAP) {
        // col fits in 16 bits (N=50000 < 65536); rowlo in bits 16..19
        bkt[((size_t)s * NB + b) * SCAP + pos] =
            make_uint2((unsigned)c | ((unsigned)(r & (RPB - 1)) << 16), __float_as_uint(v));
    } else {                          // statistically never (z ~ 6 sigma); correctness fallback
        int k = atomicAdd(ovf_n, 1);
        if (k < OVF_CAP) { ovf_row[k] = r; ovf_col[k] = c; ovf_val[k] = v; }
    }
}

// ---------------- Fused SpMM: bin bucket edges into an LDS ELL tile, then gather ----------------
// Block = one 16-row bucket. Phase A: bin ~512 bucket edges into ell_s[16][64] (LDS atomics,
// exactly the old ell_from_buckets logic -- but the global ELL array/cnt/launch are deleted).
// Phase B: wave w handles rows w*4..w*4+3 with the proven 8-deep readlane gather (full 128 ch,
// one 512B X row per load instruction, 8 gathers in flight per wave).
__global__ __launch_bounds__(256) void spmm_fused(
    const uint2* __restrict__ bkt,
    const int*   __restrict__ btail,
    int* __restrict__ ovf_n, int* __restrict__ ovf_row,
    int* __restrict__ ovf_col, float* __restrict__ ovf_val,
    const float* __restrict__ X,          // row stride x_stride (floats)
    const float* __restrict__ row_scale,  // nullptr or theta[N]
    float*       __restrict__ out,        // row stride out_stride (floats)
    int x_stride, int out_stride)
{
    __shared__ __align__(16) uint2 ell_s[RPB][ELL_W];   // 8 KB
    __shared__ int lcnt[RPB];

    int t  = threadIdx.x;
    int b  = blockIdx.x;              // bucket id, grid == NB
    int r0 = b * RPB;

    if (t < RPB) lcnt[t] = 0;
    __syncthreads();

    for (int s = 0; s < NSUB; ++s) {
        int n = btail[(s * NB + b) * BT_STRIDE];
        if (n > SCAP) n = SCAP;
        for (int i = t; i < n; i += 256) {
            uint2 rec = bkt[((size_t)s * NB + b) * SCAP + i];
            int lr = (int)(rec.x >> 16);
            int pos = atomicAdd(&lcnt[lr], 1);
            if (pos < ELL_W) {
                ell_s[lr][pos] = make_uint2(rec.x & 0xFFFFu, rec.y);
            } else {                  // row degree > 64: ~never; correctness fallback
                int k = atomicAdd(ovf_n, 1);
                if (k < OVF_CAP) {
                    ovf_row[k] = r0 + lr;
                    ovf_col[k] = (int)(rec.x & 0xFFFFu);
                    ovf_val[k] = __uint_as_float(rec.y);
                }
            }
        }
    }
    __syncthreads();                  // also drains this block's ovf stores (vmcnt before barrier)

    int w    = t >> 6;                // wave 0..3
    int lane = t & 63;
    int m = *ovf_n;                   // >= index of any entry this block pushed
    if (m > OVF_CAP) m = OVF_CAP;

    for (int rr = 0; rr < 4; ++rr) {
        int lr  = w * 4 + rr;
        int row = r0 + lr;
        int n   = lcnt[lr];
        int ncl = n < ELL_W ? n : ELL_W;

        uint2 rec = ell_s[lr][lane];  // lanes >= ncl read stale LDS; never broadcast below
        int mycol = (int)rec.x;
        int myval = (int)rec.y;

        float2 acc = {0.f, 0.f};
        int j = 0;
        for (; j + 8 <= ncl; j += 8) {
            float2 x[8];
            #pragma unroll
            for (int u = 0; u < 8; ++u) {
                int c = __builtin_amdgcn_readlane(mycol, j + u);   // SGPR col
                x[u] = ((const float2*)(X + (size_t)c * x_stride))[lane];
            }
            #pragma unroll
            for (int u = 0; u < 8; ++u) {
                float v = __uint_as_float((unsigned)__builtin_amdgcn_readlane(myval, j + u));
                acc.x = fmaf(v, x[u].x, acc.x);
                acc.y = fmaf(v, x[u].y, acc.y);
            }
        }
        for (; j < ncl; ++j) {
            int   c = __builtin_amdgcn_readlane(mycol, j);
            float v = __uint_as_float((unsigned)__builtin_amdgcn_readlane(myval, j));
            float2 x = ((const float2*)(X + (size_t)c * x_stride))[lane];
            acc.x = fmaf(v, x.x, acc.x);
            acc.y = fmaf(v, x.y, acc.y);
        }

        if (m > 0) {                  // expected 0; scan only if global overflow occurred
            for (int k = 0; k < m; ++k) {
                if (ovf_row[k] == row) {
                    float v = ovf_val[k];
                    float2 x = ((const float2*)(X + (size_t)ovf_col[k] * x_stride))[lane];
                    acc.x = fmaf(v, x.x, acc.x);
                    acc.y = fmaf(v, x.y, acc.y);
                }
            }
        }

        if (row_scale) {
            float s = row_scale[row];
            acc.x *= s;
            acc.y *= s;
        }
        ((float2*)(out + (size_t)row * out_stride))[lane] = acc;
    }
}

extern "C" void kernel_launch(void* const* d_in, const int* in_sizes, int n_in,
                              void* d_out, int out_size, void* d_ws, size_t ws_size,
                              hipStream_t stream) {
    const int*   phi_idx  = (const int*)  d_in[0];   // [L, 2, E]
    const float* phi_val  = (const float*)d_in[1];   // [L, E]
    const int*   pinv_idx = (const int*)  d_in[2];   // [L, 2, E]
    const float* pinv_val = (const float*)d_in[3];   // [L, E]
    const float* feat     = (const float*)d_in[4];   // [N, L, C] == [NL, C]
    const float* W        = (const float*)d_in[5];   // [C, C]
    const float* theta    = (const float*)d_in[6];   // [N]
    float* out = (float*)d_out;

    // Workspace layout (~49.7 MB; global ELL array + cnt eliminated)
    float* Z       = (float*)d_ws;                               // N*C f32          25.6 MB
    uint2* bkt     = (uint2*)(Z + (size_t)N_NODES * C);          // NSUB*NB*SCAP     22.4 MB
    int*   btail   = (int*)(bkt + (size_t)NSUB * NB * SCAP);     // NSUB*NB*16        1.6 MB
    int*   ovf_n   = btail + NSUB * NB * BT_STRIDE;              // 1 (adjacent for single memset)
    int*   ovf_row = ovf_n + 1;
    int*   ovf_col = ovf_row + OVF_CAP;
    float* ovf_val = (float*)(ovf_col + OVF_CAP);

    dim3 blk(256);
    int gemmGrid = (NL + 127) / 128;          // 1563
    int partGrid = (E_NNZ + 255) / 256;       // 6250
    int spmmGrid = NB;                        // 3125: one 16-row bucket per block

    // All four scales' feat @ W in one shot, written into out (scratch; each slice
    // out[:,l,:] is consumed by scale-l spmm-1 strictly before spmm-2 overwrites it).
    gemm_all<<<gemmGrid, blk, 0, stream>>>(feat, W, out);

    for (int l = 0; l < L_SCALES; ++l) {
        // ---- Z = theta (.) (phi_inv_l @ out[:,l,:]) ----
        hipMemsetAsync(btail, 0, (NSUB * NB * BT_STRIDE + 1) * sizeof(int), stream);
        partition_edges<<<partGrid, blk, 0, stream>>>(
            pinv_idx + (size_t)l * 2 * E_NNZ,
            pinv_idx + (size_t)l * 2 * E_NNZ + E_NNZ,
            pinv_val + (size_t)l * E_NNZ,
            bkt, btail, ovf_n, ovf_row, ovf_col, ovf_val);
        spmm_fused<<<spmmGrid, blk, 0, stream>>>(
            bkt, btail, ovf_n, ovf_row, ovf_col, ovf_val,
            out + (size_t)l * C, theta, Z, L_SCALES * C, C);

        // ---- out[:,l,:] = phi_l @ Z ----
        hipMemsetAsync(btail, 0, (NSUB * NB * BT_STRIDE + 1) * sizeof(int), stream);
        partition_edges<<<partGrid, blk, 0, stream>>>(
            phi_idx + (size_t)l * 2 * E_NNZ,
            phi_idx + (size_t)l * 2 * E_NNZ + E_NNZ,
            phi_val + (size_t)l * E_NNZ,
            bkt, btail, ovf_n, ovf_row, ovf_col, ovf_val);
        spmm_fused<<<spmmGrid, blk, 0, stream>>>(
            bkt, btail, ovf_n, ovf_row, ovf_col, ovf_val,
            Z, nullptr, out + (size_t)l * C, C, L_SCALES * C);
    }
}